// Round 2
// baseline (388.935 us; speedup 1.0000x reference)
//
#include <hip/hip_runtime.h>
#include <hip/hip_bf16.h>
#include <cstdint>

#define HH 4
#define CC 64
#define KDIM 256   // IN_CH
#define NOUT 256   // H*C

// ---------------- GEMM: Wh = X @ W^T ----------------
// X: [M, 256], W: [256, 256] row-major; Wh[m, j] = sum_k X[m,k] * W[j,k]
__global__ __launch_bounds__(256)
void gemm_xwt(const float* __restrict__ X, const float* __restrict__ W,
              float* __restrict__ Wh, int M) {
  __shared__ float As[16][64];   // As[k][m]
  __shared__ float Bs[16][64];   // Bs[k][j]
  const int tid = threadIdx.x;
  const int tx = tid & 15, ty = tid >> 4;
  const int row0 = blockIdx.y * 64;
  const int col0 = blockIdx.x * 64;
  const int lr = tid >> 2;          // 0..63
  const int lk = (tid & 3) * 4;     // 0,4,8,12
  float acc[4][4] = {};
  for (int k0 = 0; k0 < KDIM; k0 += 16) {
    float4 av = make_float4(0.f, 0.f, 0.f, 0.f);
    if (row0 + lr < M)
      av = *(const float4*)&X[(size_t)(row0 + lr) * KDIM + k0 + lk];
    As[lk + 0][lr] = av.x; As[lk + 1][lr] = av.y;
    As[lk + 2][lr] = av.z; As[lk + 3][lr] = av.w;
    float4 bv = *(const float4*)&W[(size_t)(col0 + lr) * KDIM + k0 + lk];
    Bs[lk + 0][lr] = bv.x; Bs[lk + 1][lr] = bv.y;
    Bs[lk + 2][lr] = bv.z; Bs[lk + 3][lr] = bv.w;
    __syncthreads();
#pragma unroll
    for (int kk = 0; kk < 16; ++kk) {
      float4 a = *(const float4*)&As[kk][ty * 4];
      float4 b = *(const float4*)&Bs[kk][tx * 4];
      acc[0][0] += a.x * b.x; acc[0][1] += a.x * b.y; acc[0][2] += a.x * b.z; acc[0][3] += a.x * b.w;
      acc[1][0] += a.y * b.x; acc[1][1] += a.y * b.y; acc[1][2] += a.y * b.z; acc[1][3] += a.y * b.w;
      acc[2][0] += a.z * b.x; acc[2][1] += a.z * b.y; acc[2][2] += a.z * b.z; acc[2][3] += a.z * b.w;
      acc[3][0] += a.w * b.x; acc[3][1] += a.w * b.y; acc[3][2] += a.w * b.z; acc[3][3] += a.w * b.w;
    }
    __syncthreads();
  }
#pragma unroll
  for (int i = 0; i < 4; ++i) {
    int r = row0 + ty * 4 + i;
    if (r < M) {
      float4 v = make_float4(acc[i][0], acc[i][1], acc[i][2], acc[i][3]);
      *(float4*)&Wh[(size_t)r * NOUT + col0 + tx * 4] = v;
    }
  }
}

// ---------------- per-node attention scores ----------------
__global__ __launch_bounds__(256)
void node_scores(const float* __restrict__ Wh, const float* __restrict__ att,
                 float* __restrict__ s_src, float* __restrict__ s_dst, int N) {
  int wid = (int)((blockIdx.x * (size_t)blockDim.x + threadIdx.x) >> 6);
  int lane = threadIdx.x & 63;
  if (wid >= N) return;
  int h = lane >> 4;
  int cg = (lane & 15) * 4;
  float4 w = *(const float4*)&Wh[(size_t)wid * NOUT + h * CC + cg];
  float4 as = *(const float4*)&att[h * 2 * CC + cg];
  float4 ad = *(const float4*)&att[h * 2 * CC + CC + cg];
  float vs = w.x * as.x + w.y * as.y + w.z * as.z + w.w * as.w;
  float vd = w.x * ad.x + w.y * ad.y + w.z * ad.z + w.w * ad.w;
#pragma unroll
  for (int off = 1; off < 16; off <<= 1) {
    vs += __shfl_xor(vs, off);
    vd += __shfl_xor(vd, off);
  }
  if ((lane & 15) == 0) {
    s_src[wid * HH + h] = vs;
    s_dst[wid * HH + h] = vd;
  }
}

__device__ __forceinline__ unsigned enc_f32(float f) {
  unsigned b = __float_as_uint(f);
  return (b & 0x80000000u) ? ~b : (b | 0x80000000u);
}
__device__ __forceinline__ float dec_f32(unsigned e) {
  unsigned b = (e & 0x80000000u) ? (e & 0x7fffffffu) : ~e;
  return __uint_as_float(b);
}

// ---------------- pass 1: leaky logits -> segment max (+ degree hist) ----------------
__global__ __launch_bounds__(256)
void edge_max_kernel(const int* __restrict__ ei, const float* __restrict__ s_src,
                     const float* __restrict__ s_dst, unsigned* __restrict__ emax,
                     int* __restrict__ deg, int E, int N) {
  int t = blockIdx.x * blockDim.x + threadIdx.x;
  int e = t >> 2, h = t & 3;
  if (e >= E) return;
  int s = ei[e];
  int d = ei[E + e];
  if ((unsigned)s >= (unsigned)N || (unsigned)d >= (unsigned)N) return;  // safety
  float v = s_src[s * HH + h] + s_dst[d * HH + h];
  v = v > 0.f ? v : 0.2f * v;
  atomicMax(&emax[d * HH + h], enc_f32(v));
  if (h == 0) atomicAdd(&deg[d], 1);
}

// ---------------- scan (3 kernels) ----------------
__global__ void scan_partial(const int* __restrict__ deg, int* __restrict__ bsums, int N) {
  __shared__ int sd[256];
  int i = blockIdx.x * 256 + threadIdx.x;
  sd[threadIdx.x] = (i < N) ? deg[i] : 0;
  __syncthreads();
  for (int s = 128; s > 0; s >>= 1) {
    if (threadIdx.x < s) sd[threadIdx.x] += sd[threadIdx.x + s];
    __syncthreads();
  }
  if (threadIdx.x == 0) bsums[blockIdx.x] = sd[0];
}

__global__ void scan_bsums(int* __restrict__ bsums, int NB) {
  __shared__ int sd[256];
  int t = threadIdx.x;
  int v = (t < NB) ? bsums[t] : 0;
  sd[t] = v;
  __syncthreads();
  for (int off = 1; off < 256; off <<= 1) {
    int add = (t >= off) ? sd[t - off] : 0;
    __syncthreads();
    sd[t] += add;
    __syncthreads();
  }
  bsums[t] = sd[t] - v;  // exclusive
}

__global__ void scan_final(const int* __restrict__ deg, const int* __restrict__ bsums,
                           int* __restrict__ row_ptr, int* __restrict__ cursor, int N) {
  __shared__ int sd[256];
  int t = threadIdx.x;
  int i = blockIdx.x * 256 + t;
  int v = (i < N) ? deg[i] : 0;
  sd[t] = v;
  __syncthreads();
  for (int off = 1; off < 256; off <<= 1) {
    int add = (t >= off) ? sd[t - off] : 0;
    __syncthreads();
    sd[t] += add;
    __syncthreads();
  }
  int excl = sd[t] - v + bsums[blockIdx.x];
  if (i < N) { row_ptr[i] = excl; cursor[i] = excl; }
  if (i == N - 1) row_ptr[N] = excl + v;
}

// ---------------- pass 2: exp(e - max), denom accumulate, CSR scatter ----------------
__global__ __launch_bounds__(256)
void edge_exp_kernel(const int* __restrict__ ei, const float* __restrict__ s_src,
                     const float* __restrict__ s_dst, const unsigned* __restrict__ emax,
                     float* __restrict__ denom, float* __restrict__ e_exp_csr,
                     int* __restrict__ cursor, int* __restrict__ csr_src, int E, int N) {
  int t = blockIdx.x * blockDim.x + threadIdx.x;
  int e = t >> 2, h = t & 3;
  if (e >= E) return;
  int s = ei[e];
  int d = ei[E + e];
  if ((unsigned)s >= (unsigned)N || (unsigned)d >= (unsigned)N) return;  // safety
  float v = s_src[s * HH + h] + s_dst[d * HH + h];
  v = v > 0.f ? v : 0.2f * v;
  float m = dec_f32(emax[d * HH + h]);
  float p = expf(v - m);
  atomicAdd(&denom[d * HH + h], p);
  int pos = 0;
  if (h == 0) pos = atomicAdd(&cursor[d], 1);
  pos = __shfl(pos, (threadIdx.x & 63) & ~3);
  e_exp_csr[(size_t)pos * HH + h] = p;
  if (h == 0) csr_src[pos] = s;
}

// ---------------- pass 3: CSR aggregation + ELU ----------------
__global__ __launch_bounds__(256)
void aggregate(const float* __restrict__ Wh, const float* __restrict__ e_exp_csr,
               const float* __restrict__ denom, const int* __restrict__ row_ptr,
               const int* __restrict__ csr_src, float* __restrict__ out, int N) {
  int wid = (int)((blockIdx.x * (size_t)blockDim.x + threadIdx.x) >> 6);
  int lane = threadIdx.x & 63;
  if (wid >= N) return;
  int h = lane >> 4;
  int start = row_ptr[wid];
  int end = row_ptr[wid + 1];
  float rd = 1.0f / (denom[wid * HH + h] + 1e-16f);
  float4 acc = make_float4(0.f, 0.f, 0.f, 0.f);
  for (int idx = start; idx < end; ++idx) {
    int s = csr_src[idx];
    float alpha = e_exp_csr[(size_t)idx * HH + h] * rd;
    float4 wv = *(const float4*)&Wh[(size_t)s * NOUT + lane * 4];
    acc.x += alpha * wv.x;
    acc.y += alpha * wv.y;
    acc.z += alpha * wv.z;
    acc.w += alpha * wv.w;
  }
  float4 o;
  o.x = acc.x > 0.f ? acc.x : expm1f(acc.x);
  o.y = acc.y > 0.f ? acc.y : expm1f(acc.y);
  o.z = acc.z > 0.f ? acc.z : expm1f(acc.z);
  o.w = acc.w > 0.f ? acc.w : expm1f(acc.w);
  *(float4*)&out[(size_t)wid * NOUT + lane * 4] = o;
}

extern "C" void kernel_launch(void* const* d_in, const int* in_sizes, int n_in,
                              void* d_out, int out_size, void* d_ws, size_t ws_size,
                              hipStream_t stream) {
  const float* x = (const float*)d_in[0];
  const int* ei = (const int*)d_in[1];   // harness converts integer inputs to int32
  const float* W = (const float*)d_in[2];
  const float* att = (const float*)d_in[3];
  float* out = (float*)d_out;
  const int N = in_sizes[0] / KDIM;
  const int E = in_sizes[1] / 2;

  char* p = (char*)d_ws;
  auto alloc = [&](size_t bytes) {
    char* r = p;
    p += (bytes + 255) & ~(size_t)255;
    return r;
  };
  float* Wh      = (float*)alloc((size_t)N * NOUT * 4);
  float* s_src   = (float*)alloc((size_t)N * HH * 4);
  float* s_dst   = (float*)alloc((size_t)N * HH * 4);
  char* zbase = p;
  float* denom   = (float*)alloc((size_t)N * HH * 4);
  unsigned* emax = (unsigned*)alloc((size_t)N * HH * 4);
  int* deg       = (int*)alloc((size_t)N * 4);
  size_t zbytes  = (size_t)(p - zbase);
  int* row_ptr   = (int*)alloc((size_t)(N + 1) * 4);
  int* cursor    = (int*)alloc((size_t)N * 4);
  int* bsums     = (int*)alloc(256 * 4);
  float* e_exp   = (float*)alloc((size_t)E * HH * 4);
  int* csr_src   = (int*)alloc((size_t)E * 4);

  hipMemsetAsync(zbase, 0, zbytes, stream);

  dim3 gg(NOUT / 64, (N + 63) / 64);
  gemm_xwt<<<gg, 256, 0, stream>>>(x, W, Wh, N);

  node_scores<<<(N + 3) / 4, 256, 0, stream>>>(Wh, att, s_src, s_dst, N);

  int eblocks = (int)(((size_t)E * HH + 255) / 256);
  edge_max_kernel<<<eblocks, 256, 0, stream>>>(ei, s_src, s_dst, emax, deg, E, N);

  int NB = (N + 255) / 256;
  scan_partial<<<NB, 256, 0, stream>>>(deg, bsums, N);
  scan_bsums<<<1, 256, 0, stream>>>(bsums, NB);
  scan_final<<<NB, 256, 0, stream>>>(deg, bsums, row_ptr, cursor, N);

  edge_exp_kernel<<<eblocks, 256, 0, stream>>>(ei, s_src, s_dst, emax, denom, e_exp,
                                               cursor, csr_src, E, N);

  aggregate<<<(N + 3) / 4, 256, 0, stream>>>(Wh, e_exp, denom, row_ptr, csr_src, out, N);
}

// Round 3
// 212.487 us; speedup vs baseline: 1.8304x; 1.8304x over previous
//
#include <hip/hip_runtime.h>
#include <hip/hip_bf16.h>
#include <cstdint>

#define HH 4
#define CC 64
#define KDIM 256   // IN_CH
#define NOUT 256   // H*C
#define BM 128
#define BN 64
#define BK 64

typedef __attribute__((ext_vector_type(8))) short bf16x8;
typedef __attribute__((ext_vector_type(4))) float f32x4;
typedef unsigned short ushort_t;

__device__ __forceinline__ unsigned short f2bf(float f) {
  unsigned u = __float_as_uint(f);
  unsigned r = (u + 0x7fff + ((u >> 16) & 1)) >> 16;  // RNE
  return (unsigned short)r;
}

// ---------------- convert x, W to bf16 (pad x rows to NPAD with zeros) ----------------
__global__ __launch_bounds__(256)
void convert_bf16(const float* __restrict__ x, const float* __restrict__ W,
                  ushort_t* __restrict__ xb, ushort_t* __restrict__ Wb,
                  long long NK, long long NPK, long long WK) {
  long long i = ((long long)blockIdx.x * 256 + threadIdx.x) * 8;
  if (i < NPK) {
    uint4 o = make_uint4(0u, 0u, 0u, 0u);
    if (i < NK) {
      float4 a = *(const float4*)(x + i);
      float4 b = *(const float4*)(x + i + 4);
      o.x = (unsigned)f2bf(a.x) | ((unsigned)f2bf(a.y) << 16);
      o.y = (unsigned)f2bf(a.z) | ((unsigned)f2bf(a.w) << 16);
      o.z = (unsigned)f2bf(b.x) | ((unsigned)f2bf(b.y) << 16);
      o.w = (unsigned)f2bf(b.z) | ((unsigned)f2bf(b.w) << 16);
    }
    *(uint4*)(xb + i) = o;
  } else {
    long long j = i - NPK;
    if (j < WK) {
      float4 a = *(const float4*)(W + j);
      float4 b = *(const float4*)(W + j + 4);
      uint4 o;
      o.x = (unsigned)f2bf(a.x) | ((unsigned)f2bf(a.y) << 16);
      o.y = (unsigned)f2bf(a.z) | ((unsigned)f2bf(a.w) << 16);
      o.z = (unsigned)f2bf(b.x) | ((unsigned)f2bf(b.y) << 16);
      o.w = (unsigned)f2bf(b.z) | ((unsigned)f2bf(b.w) << 16);
      *(uint4*)(Wb + j) = o;
    }
  }
}

#define GLOAD_LDS16(g, l) \
  __builtin_amdgcn_global_load_lds((__attribute__((address_space(1))) const void*)(g), \
                                   (__attribute__((address_space(3))) void*)(l), 16, 0, 0)

// ---------------- MFMA GEMM: Wh(bf16) = xb @ Wb^T ----------------
// xb: [NPAD, 256] bf16; Wb: [256, 256] bf16 (row j = output col j, k contiguous)
__global__ __launch_bounds__(256)
void gemm_bf16(const ushort_t* __restrict__ xb, const ushort_t* __restrict__ Wb,
               ushort_t* __restrict__ Wh, int M) {
  __shared__ char lds[(BM + BN) * BK * 2];  // A: 16KB, B: 8KB
  const int tid = threadIdx.x;
  const int lane = tid & 63;
  const int w = tid >> 6;
  const int row0 = blockIdx.y * BM;
  const int col0 = blockIdx.x * BN;
  char* As = lds;
  char* Bs = lds + BM * BK * 2;

  f32x4 acc[2][4] = {};

  for (int k0 = 0; k0 < KDIM; k0 += BK) {
    // stage A: 1024 x 16B chunks, linear LDS dest, pre-swizzled global source
#pragma unroll
    for (int i = 0; i < 4; ++i) {
      int c = i * 256 + tid;
      int row = c >> 3, c16 = c & 7;
      int q = c16 ^ (row & 7);
      const ushort_t* g = xb + (size_t)(row0 + row) * KDIM + k0 + q * 8;
      GLOAD_LDS16(g, As + (i * 256 + w * 64) * 16);
    }
    // stage B: 512 x 16B chunks
#pragma unroll
    for (int i = 0; i < 2; ++i) {
      int c = i * 256 + tid;
      int row = c >> 3, c16 = c & 7;
      int q = c16 ^ (row & 7);
      const ushort_t* g = Wb + (size_t)(col0 + row) * KDIM + k0 + q * 8;
      GLOAD_LDS16(g, Bs + (i * 256 + w * 64) * 16);
    }
    __syncthreads();

#pragma unroll
    for (int kk = 0; kk < 2; ++kk) {
      bf16x8 aF[2], bF[4];
#pragma unroll
      for (int rt = 0; rt < 2; ++rt) {
        int r = w * 32 + rt * 16 + (lane & 15);
        int qq = kk * 4 + (lane >> 4);
        int phys = qq ^ (r & 7);
        aF[rt] = *(const bf16x8*)(As + r * 128 + phys * 16);
      }
#pragma unroll
      for (int ct = 0; ct < 4; ++ct) {
        int cl = ct * 16 + (lane & 15);
        int qq = kk * 4 + (lane >> 4);
        int phys = qq ^ (cl & 7);
        bF[ct] = *(const bf16x8*)(Bs + cl * 128 + phys * 16);
      }
#pragma unroll
      for (int rt = 0; rt < 2; ++rt)
#pragma unroll
        for (int ct = 0; ct < 4; ++ct)
          acc[rt][ct] = __builtin_amdgcn_mfma_f32_16x16x32_bf16(aF[rt], bF[ct], acc[rt][ct], 0, 0, 0);
    }
    __syncthreads();
  }

  // epilogue: D[row][col], col = lane&15, row = (lane>>4)*4 + reg  (m89 layout)
#pragma unroll
  for (int rt = 0; rt < 2; ++rt) {
#pragma unroll
    for (int reg = 0; reg < 4; ++reg) {
      int r = row0 + w * 32 + rt * 16 + (lane >> 4) * 4 + reg;
      if (r < M) {
#pragma unroll
        for (int ct = 0; ct < 4; ++ct) {
          int ccol = col0 + ct * 16 + (lane & 15);
          Wh[(size_t)r * NOUT + ccol] = f2bf(acc[rt][ct][reg]);
        }
      }
    }
  }
}

// ---------------- per-node attention scores (2 nodes/wave, bf16 Wh) ----------------
__global__ __launch_bounds__(256)
void node_scores(const ushort_t* __restrict__ Wh, const float* __restrict__ att,
                 float* __restrict__ s_src, float* __restrict__ s_dst, int N) {
  int waveIdx = (int)((blockIdx.x * 256 + threadIdx.x) >> 6);
  int lane = threadIdx.x & 63;
  int node = waveIdx * 2 + (lane >> 5);
  if (node >= N) return;
  int cl = lane & 31;
  int h = cl >> 3;
  int ch = cl * 8;
  int c = ch & 63;
  uint4 v = *(const uint4*)(Wh + (size_t)node * NOUT + ch);
  const float* as_ = att + h * 2 * CC + c;
  const float* ad_ = att + h * 2 * CC + CC + c;
  float vs = 0.f, vd = 0.f;
#pragma unroll
  for (int j = 0; j < 4; ++j) {
    unsigned u = ((const unsigned*)&v)[j];
    float f0 = __uint_as_float(u << 16);
    float f1 = __uint_as_float(u & 0xffff0000u);
    vs += f0 * as_[2 * j] + f1 * as_[2 * j + 1];
    vd += f0 * ad_[2 * j] + f1 * ad_[2 * j + 1];
  }
#pragma unroll
  for (int off = 1; off < 8; off <<= 1) {
    vs += __shfl_xor(vs, off);
    vd += __shfl_xor(vd, off);
  }
  if ((cl & 7) == 0) {
    s_src[node * HH + h] = vs;
    s_dst[node * HH + h] = vd;
  }
}

// ---------------- degree count ----------------
__global__ __launch_bounds__(256)
void deg_count(const int* __restrict__ ei, int* __restrict__ deg, int E) {
  int t = blockIdx.x * 256 + threadIdx.x;
  if (t < E) atomicAdd(&deg[ei[E + t]], 1);
}

// ---------------- scan (3 kernels) ----------------
__global__ void scan_partial(const int* __restrict__ deg, int* __restrict__ bsums, int N) {
  __shared__ int sd[256];
  int i = blockIdx.x * 256 + threadIdx.x;
  sd[threadIdx.x] = (i < N) ? deg[i] : 0;
  __syncthreads();
  for (int s = 128; s > 0; s >>= 1) {
    if (threadIdx.x < s) sd[threadIdx.x] += sd[threadIdx.x + s];
    __syncthreads();
  }
  if (threadIdx.x == 0) bsums[blockIdx.x] = sd[0];
}

__global__ void scan_bsums(int* __restrict__ bsums, int NB) {
  __shared__ int sd[256];
  int t = threadIdx.x;
  int v = (t < NB) ? bsums[t] : 0;
  sd[t] = v;
  __syncthreads();
  for (int off = 1; off < 256; off <<= 1) {
    int add = (t >= off) ? sd[t - off] : 0;
    __syncthreads();
    sd[t] += add;
    __syncthreads();
  }
  bsums[t] = sd[t] - v;  // exclusive
}

__global__ void scan_final(const int* __restrict__ deg, const int* __restrict__ bsums,
                           int* __restrict__ row_ptr, int* __restrict__ cursor, int N) {
  __shared__ int sd[256];
  int t = threadIdx.x;
  int i = blockIdx.x * 256 + t;
  int v = (i < N) ? deg[i] : 0;
  sd[t] = v;
  __syncthreads();
  for (int off = 1; off < 256; off <<= 1) {
    int add = (t >= off) ? sd[t - off] : 0;
    __syncthreads();
    sd[t] += add;
    __syncthreads();
  }
  int excl = sd[t] - v + bsums[blockIdx.x];
  if (i < N) { row_ptr[i] = excl; cursor[i] = excl; }
  if (i == N - 1) row_ptr[N] = excl + v;
}

// ---------------- CSR scatter (src only) ----------------
__global__ __launch_bounds__(256)
void csr_scatter(const int* __restrict__ ei, int* __restrict__ cursor,
                 int* __restrict__ csr_src, int E) {
  int t = blockIdx.x * 256 + threadIdx.x;
  if (t >= E) return;
  int s = ei[t];
  int d = ei[E + t];
  int pos = atomicAdd(&cursor[d], 1);
  csr_src[pos] = s;
}

// ---------------- aggregation: inline softmax (no max, normalize at end) + ELU ----------------
// wave = 1 dst node; halves process alternating edges; lane covers 8 channels (16B bf16).
__global__ __launch_bounds__(256)
void aggregate(const ushort_t* __restrict__ Wh, const float* __restrict__ s_src,
               const float* __restrict__ s_dst, const int* __restrict__ row_ptr,
               const int* __restrict__ csr_src, float* __restrict__ out, int N) {
  int wid = (int)((blockIdx.x * 256 + threadIdx.x) >> 6);
  int lane = threadIdx.x & 63;
  if (wid >= N) return;
  int half = lane >> 5, cl = lane & 31;
  int h = cl >> 3;
  int start = row_ptr[wid], end = row_ptr[wid + 1];
  float sd = s_dst[wid * HH + h];
  float acc[8] = {};
  float dsum = 0.f;
  for (int idx = start + half; idx < end; idx += 2) {
    int s = csr_src[idx];
    float v = s_src[s * HH + h] + sd;
    v = v > 0.f ? v : 0.2f * v;
    float p = __expf(v);
    dsum += p;
    uint4 wv = *(const uint4*)(Wh + (size_t)s * NOUT + cl * 8);
#pragma unroll
    for (int j = 0; j < 4; ++j) {
      unsigned u = ((const unsigned*)&wv)[j];
      acc[2 * j]     += p * __uint_as_float(u << 16);
      acc[2 * j + 1] += p * __uint_as_float(u & 0xffff0000u);
    }
  }
#pragma unroll
  for (int j = 0; j < 8; ++j) acc[j] += __shfl_xor(acc[j], 32);
  dsum += __shfl_xor(dsum, 32);
  if (half == 0) {
    float rd = 1.0f / (dsum + 1e-16f);
    float o[8];
#pragma unroll
    for (int j = 0; j < 8; ++j) {
      float a = acc[j] * rd;
      o[j] = a > 0.f ? a : expm1f(a);
    }
    float* op = out + (size_t)wid * NOUT + cl * 8;
    *(float4*)op = make_float4(o[0], o[1], o[2], o[3]);
    *(float4*)(op + 4) = make_float4(o[4], o[5], o[6], o[7]);
  }
}

extern "C" void kernel_launch(void* const* d_in, const int* in_sizes, int n_in,
                              void* d_out, int out_size, void* d_ws, size_t ws_size,
                              hipStream_t stream) {
  const float* x = (const float*)d_in[0];
  const int* ei = (const int*)d_in[1];
  const float* W = (const float*)d_in[2];
  const float* att = (const float*)d_in[3];
  float* out = (float*)d_out;
  const int N = in_sizes[0] / KDIM;
  const int E = in_sizes[1] / 2;
  const int NPAD = ((N + BM - 1) / BM) * BM;
  const long long NK = (long long)N * KDIM;
  const long long NPK = (long long)NPAD * KDIM;
  const long long WK = (long long)NOUT * KDIM;

  char* p = (char*)d_ws;
  auto alloc = [&](size_t bytes) {
    char* r = p;
    p += (bytes + 255) & ~(size_t)255;
    return r;
  };
  ushort_t* xb   = (ushort_t*)alloc((size_t)NPK * 2);
  ushort_t* Wb   = (ushort_t*)alloc((size_t)WK * 2);
  ushort_t* Wh   = (ushort_t*)alloc((size_t)NPK * 2);
  float* s_src   = (float*)alloc((size_t)N * HH * 4);
  float* s_dst   = (float*)alloc((size_t)N * HH * 4);
  int* deg       = (int*)alloc((size_t)N * 4);
  int* row_ptr   = (int*)alloc((size_t)(N + 1) * 4);
  int* cursor    = (int*)alloc((size_t)N * 4);
  int* bsums     = (int*)alloc(256 * 4);
  int* csr_src   = (int*)alloc((size_t)E * 4);

  hipMemsetAsync(deg, 0, (size_t)N * 4, stream);

  long long tot8 = (NPK + WK) / 8;
  int cblocks = (int)((tot8 + 255) / 256);
  convert_bf16<<<cblocks, 256, 0, stream>>>(x, W, xb, Wb, NK, NPK, WK);

  dim3 gg(NOUT / BN, NPAD / BM);
  gemm_bf16<<<gg, 256, 0, stream>>>(xb, Wb, Wh, N);

  node_scores<<<(N + 7) / 8, 256, 0, stream>>>(Wh, att, s_src, s_dst, N);

  int eblocks = (E + 255) / 256;
  deg_count<<<eblocks, 256, 0, stream>>>(ei, deg, E);

  int NB = (N + 255) / 256;
  scan_partial<<<NB, 256, 0, stream>>>(deg, bsums, N);
  scan_bsums<<<1, 256, 0, stream>>>(bsums, NB);
  scan_final<<<NB, 256, 0, stream>>>(deg, bsums, row_ptr, cursor, N);

  csr_scatter<<<eblocks, 256, 0, stream>>>(ei, cursor, csr_src, E);

  aggregate<<<(N + 3) / 4, 256, 0, stream>>>(Wh, s_src, s_dst, row_ptr, csr_src, out, N);
}

// Round 5
// 189.870 us; speedup vs baseline: 2.0484x; 1.1191x over previous
//
#include <hip/hip_runtime.h>
#include <hip/hip_bf16.h>
#include <cstdint>

#define HH 4
#define CC 64
#define KDIM 256   // IN_CH
#define NOUT 256   // H*C
#define BM 128
#define BN 64
#define BK 64

typedef __attribute__((ext_vector_type(8))) short bf16x8;
typedef __attribute__((ext_vector_type(4))) float f32x4;
typedef unsigned short ushort_t;

__device__ __forceinline__ unsigned short f2bf(float f) {
  unsigned u = __float_as_uint(f);
  unsigned r = (u + 0x7fff + ((u >> 16) & 1)) >> 16;  // RNE
  return (unsigned short)r;
}

// ---------------- fused: convert x,W to bf16 (+pad) AND degree count ----------------
__global__ __launch_bounds__(256)
void convert_and_deg(const float* __restrict__ x, const float* __restrict__ W,
                     ushort_t* __restrict__ xb, ushort_t* __restrict__ Wb,
                     const int* __restrict__ ei, int* __restrict__ deg,
                     long long NK, long long NPK, long long WK, int cblocks, int E) {
  if ((int)blockIdx.x < cblocks) {
    long long i = ((long long)blockIdx.x * 256 + threadIdx.x) * 8;
    if (i < NPK) {
      uint4 o = make_uint4(0u, 0u, 0u, 0u);
      if (i < NK) {
        float4 a = *(const float4*)(x + i);
        float4 b = *(const float4*)(x + i + 4);
        o.x = (unsigned)f2bf(a.x) | ((unsigned)f2bf(a.y) << 16);
        o.y = (unsigned)f2bf(a.z) | ((unsigned)f2bf(a.w) << 16);
        o.z = (unsigned)f2bf(b.x) | ((unsigned)f2bf(b.y) << 16);
        o.w = (unsigned)f2bf(b.z) | ((unsigned)f2bf(b.w) << 16);
      }
      *(uint4*)(xb + i) = o;
    } else {
      long long j = i - NPK;
      if (j < WK) {
        float4 a = *(const float4*)(W + j);
        float4 b = *(const float4*)(W + j + 4);
        uint4 o;
        o.x = (unsigned)f2bf(a.x) | ((unsigned)f2bf(a.y) << 16);
        o.y = (unsigned)f2bf(a.z) | ((unsigned)f2bf(a.w) << 16);
        o.z = (unsigned)f2bf(b.x) | ((unsigned)f2bf(b.y) << 16);
        o.w = (unsigned)f2bf(b.z) | ((unsigned)f2bf(b.w) << 16);
        *(uint4*)(Wb + j) = o;
      }
    }
  } else {
    int t = ((int)blockIdx.x - cblocks) * 256 + threadIdx.x;
    if (t < E) atomicAdd(&deg[ei[E + t]], 1);
  }
}

#define GLOAD_LDS16(g, l) \
  __builtin_amdgcn_global_load_lds((__attribute__((address_space(1))) const void*)(g), \
                                   (__attribute__((address_space(3))) void*)(l), 16, 0, 0)

// ---------------- MFMA GEMM: Wh(bf16) = xb @ Wb^T, with fused attention scores ----------------
// Block covers BN=64 cols == exactly one head h = col0>>6.
__global__ __launch_bounds__(256)
void gemm_bf16(const ushort_t* __restrict__ xb, const ushort_t* __restrict__ Wb,
               ushort_t* __restrict__ Wh, float* __restrict__ s_src,
               float* __restrict__ s_dst, const float* __restrict__ att, int M) {
  __shared__ char lds[(BM + BN) * BK * 2];  // A: 16KB, B: 8KB
  const int tid = threadIdx.x;
  const int lane = tid & 63;
  const int w = tid >> 6;
  const int row0 = blockIdx.y * BM;
  const int col0 = blockIdx.x * BN;
  char* As = lds;
  char* Bs = lds + BM * BK * 2;

  f32x4 acc[2][4] = {};

  for (int k0 = 0; k0 < KDIM; k0 += BK) {
#pragma unroll
    for (int i = 0; i < 4; ++i) {
      int c = i * 256 + tid;
      int row = c >> 3, c16 = c & 7;
      int q = c16 ^ (row & 7);
      const ushort_t* g = xb + (size_t)(row0 + row) * KDIM + k0 + q * 8;
      GLOAD_LDS16(g, As + (i * 256 + w * 64) * 16);
    }
#pragma unroll
    for (int i = 0; i < 2; ++i) {
      int c = i * 256 + tid;
      int row = c >> 3, c16 = c & 7;
      int q = c16 ^ (row & 7);
      const ushort_t* g = Wb + (size_t)(col0 + row) * KDIM + k0 + q * 8;
      GLOAD_LDS16(g, Bs + (i * 256 + w * 64) * 16);
    }
    __syncthreads();

#pragma unroll
    for (int kk = 0; kk < 2; ++kk) {
      bf16x8 aF[2], bF[4];
#pragma unroll
      for (int rt = 0; rt < 2; ++rt) {
        int r = w * 32 + rt * 16 + (lane & 15);
        int qq = kk * 4 + (lane >> 4);
        int phys = qq ^ (r & 7);
        aF[rt] = *(const bf16x8*)(As + r * 128 + phys * 16);
      }
#pragma unroll
      for (int ct = 0; ct < 4; ++ct) {
        int cl = ct * 16 + (lane & 15);
        int qq = kk * 4 + (lane >> 4);
        int phys = qq ^ (cl & 7);
        bF[ct] = *(const bf16x8*)(Bs + cl * 128 + phys * 16);
      }
#pragma unroll
      for (int rt = 0; rt < 2; ++rt)
#pragma unroll
        for (int ct = 0; ct < 4; ++ct)
          acc[rt][ct] = __builtin_amdgcn_mfma_f32_16x16x32_bf16(aF[rt], bF[ct], acc[rt][ct], 0, 0, 0);
    }
    __syncthreads();
  }

  // ---- fused per-node attention scores for head h = col0>>6 ----
  const int h = col0 >> 6;
  float att_s[4], att_d[4];
#pragma unroll
  for (int ct = 0; ct < 4; ++ct) {
    att_s[ct] = att[h * 2 * CC + ct * 16 + (lane & 15)];
    att_d[ct] = att[h * 2 * CC + CC + ct * 16 + (lane & 15)];
  }
#pragma unroll
  for (int rt = 0; rt < 2; ++rt) {
#pragma unroll
    for (int reg = 0; reg < 4; ++reg) {
      float ls = 0.f, ld_ = 0.f;
#pragma unroll
      for (int ct = 0; ct < 4; ++ct) {
        float a = acc[rt][ct][reg];
        ls += a * att_s[ct];
        ld_ += a * att_d[ct];
      }
#pragma unroll
      for (int off = 1; off < 16; off <<= 1) {
        ls += __shfl_xor(ls, off);
        ld_ += __shfl_xor(ld_, off);
      }
      int r = row0 + w * 32 + rt * 16 + (lane >> 4) * 4 + reg;
      if ((lane & 15) == 0 && r < M) {
        s_src[r * HH + h] = ls;
        s_dst[r * HH + h] = ld_;
      }
    }
  }

  // ---- Wh store (m89 layout: col=lane&15, row=(lane>>4)*4+reg) ----
#pragma unroll
  for (int rt = 0; rt < 2; ++rt) {
#pragma unroll
    for (int reg = 0; reg < 4; ++reg) {
      int r = row0 + w * 32 + rt * 16 + (lane >> 4) * 4 + reg;
      if (r < M) {
#pragma unroll
        for (int ct = 0; ct < 4; ++ct) {
          int ccol = col0 + ct * 16 + (lane & 15);
          Wh[(size_t)r * NOUT + ccol] = f2bf(acc[rt][ct][reg]);
        }
      }
    }
  }
}

// ---------------- scan (3 kernels) ----------------
__global__ void scan_partial(const int* __restrict__ deg, int* __restrict__ bsums, int N) {
  __shared__ int sd[256];
  int i = blockIdx.x * 256 + threadIdx.x;
  sd[threadIdx.x] = (i < N) ? deg[i] : 0;
  __syncthreads();
  for (int s = 128; s > 0; s >>= 1) {
    if (threadIdx.x < s) sd[threadIdx.x] += sd[threadIdx.x + s];
    __syncthreads();
  }
  if (threadIdx.x == 0) bsums[blockIdx.x] = sd[0];
}

__global__ void scan_bsums(int* __restrict__ bsums, int NB) {
  __shared__ int sd[256];
  int t = threadIdx.x;
  int v = (t < NB) ? bsums[t] : 0;
  sd[t] = v;
  __syncthreads();
  for (int off = 1; off < 256; off <<= 1) {
    int add = (t >= off) ? sd[t - off] : 0;
    __syncthreads();
    sd[t] += add;
    __syncthreads();
  }
  bsums[t] = sd[t] - v;  // exclusive
}

__global__ void scan_final(const int* __restrict__ deg, const int* __restrict__ bsums,
                           int* __restrict__ row_ptr, int* __restrict__ cursor, int N) {
  __shared__ int sd[256];
  int t = threadIdx.x;
  int i = blockIdx.x * 256 + t;
  int v = (i < N) ? deg[i] : 0;
  sd[t] = v;
  __syncthreads();
  for (int off = 1; off < 256; off <<= 1) {
    int add = (t >= off) ? sd[t - off] : 0;
    __syncthreads();
    sd[t] += add;
    __syncthreads();
  }
  int excl = sd[t] - v + bsums[blockIdx.x];
  if (i < N) { row_ptr[i] = excl; cursor[i] = excl; }
  if (i == N - 1) row_ptr[N] = excl + v;
}

// ---------------- CSR scatter + per-edge softmax numerator (all heads) ----------------
__global__ __launch_bounds__(256)
void csr_scatter(const int* __restrict__ ei, const float* __restrict__ s_src,
                 const float* __restrict__ s_dst, int* __restrict__ cursor,
                 int* __restrict__ csr_src, float4* __restrict__ e_p, int E) {
  int t = blockIdx.x * 256 + threadIdx.x;
  if (t >= E) return;
  int s = ei[t];
  int d = ei[E + t];
  int pos = atomicAdd(&cursor[d], 1);
  float4 ss = *(const float4*)&s_src[s * HH];
  float4 dd = *(const float4*)&s_dst[d * HH];
  float4 p;
  float v;
  v = ss.x + dd.x; v = v > 0.f ? v : 0.2f * v; p.x = __expf(v);
  v = ss.y + dd.y; v = v > 0.f ? v : 0.2f * v; p.y = __expf(v);
  v = ss.z + dd.z; v = v > 0.f ? v : 0.2f * v; p.z = __expf(v);
  v = ss.w + dd.w; v = v > 0.f ? v : 0.2f * v; p.w = __expf(v);
  csr_src[pos] = s;
  e_p[pos] = p;
}

// ---------------- aggregation: streaming p, gathered Wh rows, unroll x2 ----------------
__global__ __launch_bounds__(256)
void aggregate(const ushort_t* __restrict__ Wh, const float* __restrict__ e_p,
               const int* __restrict__ row_ptr, const int* __restrict__ csr_src,
               float* __restrict__ out, int N) {
  int wid = (int)((blockIdx.x * 256 + threadIdx.x) >> 6);
  int lane = threadIdx.x & 63;
  if (wid >= N) return;
  int half = lane >> 5, cl = lane & 31;
  int h = cl >> 3;
  int start = row_ptr[wid], end = row_ptr[wid + 1];
  float acc[8] = {};
  float dsum = 0.f;
  int idx = start + half;
  // two edges in flight per half (4 per wave)
  for (; idx + 2 < end; idx += 4) {
    int s0 = csr_src[idx];
    int s1 = csr_src[idx + 2];
    float p0 = e_p[idx * 4 + h];
    float p1 = e_p[(idx + 2) * 4 + h];
    uint4 w0 = *(const uint4*)(Wh + (size_t)s0 * NOUT + cl * 8);
    uint4 w1 = *(const uint4*)(Wh + (size_t)s1 * NOUT + cl * 8);
    dsum += p0 + p1;
#pragma unroll
    for (int j = 0; j < 4; ++j) {
      unsigned u0 = ((const unsigned*)&w0)[j];
      unsigned u1 = ((const unsigned*)&w1)[j];
      acc[2 * j]     += p0 * __uint_as_float(u0 << 16) + p1 * __uint_as_float(u1 << 16);
      acc[2 * j + 1] += p0 * __uint_as_float(u0 & 0xffff0000u) + p1 * __uint_as_float(u1 & 0xffff0000u);
    }
  }
  if (idx < end) {
    int s0 = csr_src[idx];
    float p0 = e_p[idx * 4 + h];
    uint4 w0 = *(const uint4*)(Wh + (size_t)s0 * NOUT + cl * 8);
    dsum += p0;
#pragma unroll
    for (int j = 0; j < 4; ++j) {
      unsigned u0 = ((const unsigned*)&w0)[j];
      acc[2 * j]     += p0 * __uint_as_float(u0 << 16);
      acc[2 * j + 1] += p0 * __uint_as_float(u0 & 0xffff0000u);
    }
  }
#pragma unroll
  for (int j = 0; j < 8; ++j) acc[j] += __shfl_xor(acc[j], 32);
  dsum += __shfl_xor(dsum, 32);
  if (half == 0) {
    float rd = 1.0f / (dsum + 1e-16f);
    float o[8];
#pragma unroll
    for (int j = 0; j < 8; ++j) {
      float a = acc[j] * rd;
      o[j] = a > 0.f ? a : expm1f(a);
    }
    float* op = out + (size_t)wid * NOUT + cl * 8;
    *(float4*)op = make_float4(o[0], o[1], o[2], o[3]);
    *(float4*)(op + 4) = make_float4(o[4], o[5], o[6], o[7]);
  }
}

extern "C" void kernel_launch(void* const* d_in, const int* in_sizes, int n_in,
                              void* d_out, int out_size, void* d_ws, size_t ws_size,
                              hipStream_t stream) {
  const float* x = (const float*)d_in[0];
  const int* ei = (const int*)d_in[1];
  const float* W = (const float*)d_in[2];
  const float* att = (const float*)d_in[3];
  float* out = (float*)d_out;
  const int N = in_sizes[0] / KDIM;
  const int E = in_sizes[1] / 2;
  const int NPAD = ((N + BM - 1) / BM) * BM;
  const long long NK = (long long)N * KDIM;
  const long long NPK = (long long)NPAD * KDIM;
  const long long WK = (long long)NOUT * KDIM;

  char* p = (char*)d_ws;
  auto alloc = [&](size_t bytes) {
    char* r = p;
    p += (bytes + 255) & ~(size_t)255;
    return r;
  };
  ushort_t* xb   = (ushort_t*)alloc((size_t)NPK * 2);
  ushort_t* Wb   = (ushort_t*)alloc((size_t)WK * 2);
  ushort_t* Wh   = (ushort_t*)alloc((size_t)NPK * 2);
  float* s_src   = (float*)alloc((size_t)N * HH * 4);
  float* s_dst   = (float*)alloc((size_t)N * HH * 4);
  int* deg       = (int*)alloc((size_t)N * 4);
  int* row_ptr   = (int*)alloc((size_t)(N + 1) * 4);
  int* cursor    = (int*)alloc((size_t)N * 4);
  int* bsums     = (int*)alloc(256 * 4);
  int* csr_src   = (int*)alloc((size_t)E * 4);
  float4* e_p    = (float4*)alloc((size_t)E * 16);

  (void)hipMemsetAsync(deg, 0, (size_t)N * 4, stream);

  long long tot8 = (NPK + WK) / 8;
  int cblocks = (int)((tot8 + 255) / 256);
  int eblocks = (E + 255) / 256;
  convert_and_deg<<<cblocks + eblocks, 256, 0, stream>>>(x, W, xb, Wb, ei, deg,
                                                         NK, NPK, WK, cblocks, E);

  dim3 gg(NOUT / BN, NPAD / BM);
  gemm_bf16<<<gg, 256, 0, stream>>>(xb, Wb, Wh, s_src, s_dst, att, N);

  int NB = (N + 255) / 256;
  scan_partial<<<NB, 256, 0, stream>>>(deg, bsums, N);
  scan_bsums<<<1, 256, 0, stream>>>(bsums, NB);
  scan_final<<<NB, 256, 0, stream>>>(deg, bsums, row_ptr, cursor, N);

  csr_scatter<<<eblocks, 256, 0, stream>>>(ei, s_src, s_dst, cursor, csr_src, e_p, E);

  aggregate<<<(N + 3) / 4, 256, 0, stream>>>(Wh, (const float*)e_p, row_ptr, csr_src, out, N);
}